// Round 1
// baseline (42.558 us; speedup 1.0000x reference)
//
#include <hip/hip_runtime.h>
#include <math.h>

#define D       256
#define STRIDE  260   // 256 + 4 floats pad: keeps 16B align, bank step = 4
#define BM      64    // tile rows (A) and cols (B)

__global__ __launch_bounds__(256)
void jaccard_kernel(const float* __restrict__ A, const float* __restrict__ B,
                    float* __restrict__ out, int N, int M) {
    extern __shared__ float lds[];
    float* ALds = lds;                      // [64][STRIDE]
    float* BLds = lds + BM * STRIDE;        // [64][STRIDE]
    float* sums = lds + 2 * BM * STRIDE;    // [128]: 0..63 = A row sums, 64..127 = B row sums

    const int bi   = blockIdx.x;
    const int bj   = blockIdx.y;
    const int tid  = threadIdx.x;
    const int lane = tid & 63;
    const int wid  = tid >> 6;

    // ---- staging: one wave stages one logical row per iteration ----
    // lane l holds floats [4l..4l+3] of the row (64 lanes * 4 = 256 = D)
    for (int r = wid; r < 2 * BM; r += 4) {
        const bool  isA = (r < BM);
        const int   row = isA ? r : (r - BM);
        const float* src = isA ? (A + (size_t)(bi * BM + row) * D)
                               : (B + (size_t)(bj * BM + row) * D);
        float4 g = *(const float4*)(src + 4 * lane);
        float4 s;
        s.x = 1.0f / (1.0f + __expf(-g.x));
        s.y = 1.0f / (1.0f + __expf(-g.y));
        s.z = 1.0f / (1.0f + __expf(-g.z));
        s.w = 1.0f / (1.0f + __expf(-g.w));
        float* dst = (isA ? ALds : BLds) + (size_t)row * STRIDE + 4 * lane;
        *(float4*)dst = s;

        // row sum via wave butterfly (64 lanes)
        float rs = (s.x + s.y) + (s.z + s.w);
        #pragma unroll
        for (int k = 32; k >= 1; k >>= 1)
            rs += __shfl_xor(rs, k, 64);
        if (lane == 0) sums[r] = rs;
    }
    __syncthreads();

    // ---- main loop: 4x4 micro-tile per thread over full D ----
    const int tx = tid & 15;   // col group
    const int ty = tid >> 4;   // row group

    const float* ap = ALds + (size_t)(ty * 4) * STRIDE;
    const float* bp = BLds + (size_t)(tx * 4) * STRIDE;

    float acc[4][4] = {};
    for (int d = 0; d < D; d += 4) {
        float4 af[4], bf[4];
        #pragma unroll
        for (int m = 0; m < 4; ++m) af[m] = *(const float4*)(ap + m * STRIDE + d);
        #pragma unroll
        for (int n = 0; n < 4; ++n) bf[n] = *(const float4*)(bp + n * STRIDE + d);
        #pragma unroll
        for (int m = 0; m < 4; ++m) {
            #pragma unroll
            for (int n = 0; n < 4; ++n) {
                float s0 = fminf(af[m].x, bf[n].x) + fminf(af[m].y, bf[n].y);
                float s1 = fminf(af[m].z, bf[n].z) + fminf(af[m].w, bf[n].w);
                acc[m][n] += s0 + s1;
            }
        }
    }

    // ---- epilogue: val = inter / (sumA + sumB - inter); write sim and sim.T ----
    float sa[4], sb[4];
    #pragma unroll
    for (int m = 0; m < 4; ++m) sa[m] = sums[ty * 4 + m];
    #pragma unroll
    for (int n = 0; n < 4; ++n) sb[n] = sums[BM + tx * 4 + n];

    float val[4][4];
    #pragma unroll
    for (int m = 0; m < 4; ++m)
        #pragma unroll
        for (int n = 0; n < 4; ++n) {
            float inter = acc[m][n];
            val[m][n] = inter / (sa[m] + sb[n] - inter);
        }

    float* outT = out + (size_t)N * M;
    const int i0 = bi * BM + ty * 4;
    const int j0 = bj * BM + tx * 4;

    // sim[i][j]: per m, float4 across n (coalesced over tx)
    #pragma unroll
    for (int m = 0; m < 4; ++m) {
        float4 v = make_float4(val[m][0], val[m][1], val[m][2], val[m][3]);
        *(float4*)(out + (size_t)(i0 + m) * M + j0) = v;
    }
    // simT[j][i]: per n, float4 across m (64B segments over ty)
    #pragma unroll
    for (int n = 0; n < 4; ++n) {
        float4 v = make_float4(val[0][n], val[1][n], val[2][n], val[3][n]);
        *(float4*)(outT + (size_t)(j0 + n) * N + i0) = v;
    }
}

extern "C" void kernel_launch(void* const* d_in, const int* in_sizes, int n_in,
                              void* d_out, int out_size, void* d_ws, size_t ws_size,
                              hipStream_t stream) {
    const float* x1 = (const float*)d_in[0];
    const float* x2 = (const float*)d_in[1];
    float* out = (float*)d_out;

    const int N = in_sizes[0] / D;   // 1024
    const int M = in_sizes[1] / D;   // 1024

    const size_t lds_bytes = (size_t)(2 * BM * STRIDE + 2 * BM) * sizeof(float); // ~133.6 KB
    hipFuncSetAttribute((const void*)jaccard_kernel,
                        hipFuncAttributeMaxDynamicSharedMemorySize, (int)lds_bytes);

    dim3 grid(N / BM, M / BM);  // 16 x 16 = 256 blocks = 1 per CU
    jaccard_kernel<<<grid, 256, lds_bytes, stream>>>(x1, x2, out, N, M);
}

// Round 2
// 33.796 us; speedup vs baseline: 1.2593x; 1.2593x over previous
//
#include <hip/hip_runtime.h>
#include <math.h>

#define D       256
#define STRIDE  260   // 256 + 4 floats pad: 16B-aligned rows, bank step 4/row
#define BM      64    // tile rows (A) and cols (B)

__device__ __forceinline__ float min4sum(float4 a, float4 b) {
    float s0 = fminf(a.x, b.x) + fminf(a.y, b.y);
    float s1 = fminf(a.z, b.z) + fminf(a.w, b.w);
    return s0 + s1;
}

__global__ __launch_bounds__(1024, 4)
void jaccard_kernel(const float* __restrict__ A, const float* __restrict__ B,
                    float* __restrict__ out, int N, int M) {
    extern __shared__ float lds[];
    float* ALds = lds;                      // [64][STRIDE]
    float* BLds = lds + BM * STRIDE;        // [64][STRIDE]
    float* sums = lds + 2 * BM * STRIDE;    // [128]: 0..63 A row sums, 64..127 B

    const int bi   = blockIdx.x;
    const int bj   = blockIdx.y;
    const int tid  = threadIdx.x;
    const int lane = tid & 63;
    const int wid  = tid >> 6;   // 0..15

    // ---- staging: 16 waves, 128 logical rows -> 8 rows per wave ----
    // lane l holds floats [4l..4l+3] of the row (64 lanes * 4 = 256 = D)
    for (int r = wid; r < 2 * BM; r += 16) {
        const bool  isA = (r < BM);
        const int   row = isA ? r : (r - BM);
        const float* src = isA ? (A + (size_t)(bi * BM + row) * D)
                               : (B + (size_t)(bj * BM + row) * D);
        float4 g = *(const float4*)(src + 4 * lane);
        float4 s;
        s.x = 1.0f / (1.0f + __expf(-g.x));
        s.y = 1.0f / (1.0f + __expf(-g.y));
        s.z = 1.0f / (1.0f + __expf(-g.z));
        s.w = 1.0f / (1.0f + __expf(-g.w));
        float* dst = (isA ? ALds : BLds) + (size_t)row * STRIDE + 4 * lane;
        *(float4*)dst = s;

        // row sum via wave butterfly (64 lanes)
        float rs = (s.x + s.y) + (s.z + s.w);
        #pragma unroll
        for (int k = 32; k >= 1; k >>= 1)
            rs += __shfl_xor(rs, k, 64);
        if (lane == 0) sums[r] = rs;
    }
    __syncthreads();

    // ---- main loop: 2x2 micro-tile per thread, 32x32 thread grid ----
    const int tx = tid & 31;   // col group: cols {tx, tx+32}
    const int ty = tid >> 5;   // row group: rows {ty, ty+32}

    const float* a0 = ALds + (size_t)ty        * STRIDE;
    const float* a1 = ALds + (size_t)(32 + ty) * STRIDE;
    const float* b0 = BLds + (size_t)tx        * STRIDE;
    const float* b1 = BLds + (size_t)(32 + tx) * STRIDE;

    float acc00 = 0.f, acc01 = 0.f, acc10 = 0.f, acc11 = 0.f;
    #pragma unroll 2
    for (int d = 0; d < D; d += 4) {
        float4 af0 = *(const float4*)(a0 + d);
        float4 af1 = *(const float4*)(a1 + d);
        float4 bf0 = *(const float4*)(b0 + d);
        float4 bf1 = *(const float4*)(b1 + d);
        acc00 += min4sum(af0, bf0);
        acc01 += min4sum(af0, bf1);
        acc10 += min4sum(af1, bf0);
        acc11 += min4sum(af1, bf1);
    }

    // ---- epilogue: val = inter / (sumA + sumB - inter) ----
    const float sa0 = sums[ty],      sa1 = sums[32 + ty];
    const float sb0 = sums[64 + tx], sb1 = sums[96 + tx];

    const float v00 = acc00 / (sa0 + sb0 - acc00);
    const float v01 = acc01 / (sa0 + sb1 - acc01);
    const float v10 = acc10 / (sa1 + sb0 - acc10);
    const float v11 = acc11 / (sa1 + sb1 - acc11);

    float* outT = out + (size_t)N * M;
    const int i0 = bi * BM + ty, i1 = i0 + 32;
    const int j0 = bj * BM + tx, j1 = j0 + 32;

    // sim[i][j]: lanes (tx) write consecutive cols -> coalesced
    out[(size_t)i0 * M + j0] = v00;
    out[(size_t)i0 * M + j1] = v01;
    out[(size_t)i1 * M + j0] = v10;
    out[(size_t)i1 * M + j1] = v11;
    // sim.T[j][i]: 2 cols per row within wave; L2 assembles lines
    outT[(size_t)j0 * N + i0] = v00;
    outT[(size_t)j1 * N + i0] = v01;
    outT[(size_t)j0 * N + i1] = v10;
    outT[(size_t)j1 * N + i1] = v11;
}

extern "C" void kernel_launch(void* const* d_in, const int* in_sizes, int n_in,
                              void* d_out, int out_size, void* d_ws, size_t ws_size,
                              hipStream_t stream) {
    const float* x1 = (const float*)d_in[0];
    const float* x2 = (const float*)d_in[1];
    float* out = (float*)d_out;

    const int N = in_sizes[0] / D;   // 1024
    const int M = in_sizes[1] / D;   // 1024

    const size_t lds_bytes = (size_t)(2 * BM * STRIDE + 2 * BM) * sizeof(float); // ~133.6 KB
    hipFuncSetAttribute((const void*)jaccard_kernel,
                        hipFuncAttributeMaxDynamicSharedMemorySize, (int)lds_bytes);

    dim3 grid(N / BM, M / BM);  // 16 x 16 = 256 blocks, 1024 threads = 16 waves/CU
    jaccard_kernel<<<grid, 1024, lds_bytes, stream>>>(x1, x2, out, N, M);
}